// Round 1
// baseline (86.785 us; speedup 1.0000x reference)
//
#include <hip/hip_runtime.h>
#include <math.h>

// Problem constants (from reference)
#define NB   64      // batch
#define CC   256     // channels
#define HH   56
#define WW   56
#define NDEM 4
#define HS   28
#define WS   28

#define HW        (HH * WW)          // 3136
#define Y_ELEMS   (NB * CC * HH * WW)  // 51380224
#define AC_ELEMS  (NDEM * CC)          // 1024
#define ASP_ELEMS (NDEM * HH * WW)     // 12544

// ---------------------------------------------------------------------------
// Kernel 1: compute sigmoid gates.
//   ac[d, c]            = sigmoid(att_channel[d, 0, c, 0, 0])
//   asp[d, h, w]        = sigmoid(att_spatial[d, 0, 0, h/2, w/2])  (nearest up)
// Both are written directly into their slots of d_out (they ARE outputs 1,2)
// and then re-read (L2-hot) by the main kernel.
// ---------------------------------------------------------------------------
__global__ void att_gates_kernel(const float* __restrict__ att_channel,
                                 const float* __restrict__ att_spatial,
                                 float* __restrict__ ac_out,    // AC_ELEMS
                                 float* __restrict__ asp_out)   // ASP_ELEMS
{
    int i = blockIdx.x * blockDim.x + threadIdx.x;
    const int total = AC_ELEMS + ASP_ELEMS;
    if (i >= total) return;
    if (i < AC_ELEMS) {
        float v = att_channel[i];
        ac_out[i] = 1.0f / (1.0f + expf(-v));
    } else {
        int j = i - AC_ELEMS;          // j = d*HW + h*WW + w
        int d = j / HW;
        int r = j - d * HW;
        int h = r / WW;
        int w = r - h * WW;
        // nearest: idx = (i * in) / out = i/2 here
        float v = att_spatial[d * (HS * WS) + (h >> 1) * WS + (w >> 1)];
        asp_out[j] = 1.0f / (1.0f + expf(-v));
    }
}

// ---------------------------------------------------------------------------
// Kernel 2: y = x * gate_c * gate_s, float4-vectorized grid-stride stream.
// ---------------------------------------------------------------------------
__global__ __launch_bounds__(256) void att_apply_kernel(
    const float4* __restrict__ x,
    const int*    __restrict__ demog,     // NB
    const float*  __restrict__ ac,        // [NDEM][CC]
    const float*  __restrict__ asp,       // [NDEM][HW]
    float4*       __restrict__ y)
{
    const int total4  = Y_ELEMS / 4;   // 12845056
    const int per_n4  = CC * HW / 4;   // 200704
    const int per_c4  = HW / 4;        // 784
    const int w4s     = WW / 4;        // 14

    int stride = gridDim.x * blockDim.x;
    for (int f = blockIdx.x * blockDim.x + threadIdx.x; f < total4; f += stride) {
        int n  = f / per_n4;
        int rn = f - n * per_n4;
        int c  = rn / per_c4;
        int p  = rn - c * per_c4;      // float4 index within the (n,c) plane
        int h  = p / w4s;
        int w4 = p - h * w4s;

        int d = demog[n];
        float gc = ac[d * CC + c];
        const float4 gs =
            *reinterpret_cast<const float4*>(&asp[d * HW + h * WW + w4 * 4]);

        float4 xv = x[f];
        float4 yv;
        yv.x = xv.x * gc * gs.x;
        yv.y = xv.y * gc * gs.y;
        yv.z = xv.z * gc * gs.z;
        yv.w = xv.w * gc * gs.w;
        y[f] = yv;
    }
}

// ---------------------------------------------------------------------------
extern "C" void kernel_launch(void* const* d_in, const int* in_sizes, int n_in,
                              void* d_out, int out_size, void* d_ws, size_t ws_size,
                              hipStream_t stream) {
    const float* x           = (const float*)d_in[0];
    const int*   demog       = (const int*)d_in[1];
    const float* att_channel = (const float*)d_in[2];
    const float* att_spatial = (const float*)d_in[3];

    float* y_out   = (float*)d_out;                       // Y_ELEMS
    float* ac_out  = y_out + Y_ELEMS;                     // AC_ELEMS
    float* asp_out = y_out + Y_ELEMS + AC_ELEMS;          // ASP_ELEMS

    // 1) gates (tiny)
    {
        int total  = AC_ELEMS + ASP_ELEMS;
        int blocks = (total + 255) / 256;
        att_gates_kernel<<<blocks, 256, 0, stream>>>(att_channel, att_spatial,
                                                     ac_out, asp_out);
    }

    // 2) main stream kernel
    {
        const int total4 = Y_ELEMS / 4;
        int blocks = 4096;                 // 256 CUs * 16 blocks, grid-stride
        if (blocks * 256 > total4) blocks = (total4 + 255) / 256;
        att_apply_kernel<<<blocks, 256, 0, stream>>>(
            (const float4*)x, demog, ac_out, asp_out, (float4*)y_out);
    }
}

// Round 3
// 76.670 us; speedup vs baseline: 1.1319x; 1.1319x over previous
//
#include <hip/hip_runtime.h>
#include <math.h>

// Problem constants (from reference)
#define NB   64      // batch
#define CC   256     // channels
#define HH   56
#define WW   56
#define NDEM 4
#define HS   28
#define WS   28

#define HW        (HH * WW)            // 3136
#define HW4       (HW / 4)             // 784 float4s per plane
#define Y_ELEMS   (NB * CC * HH * WW)  // 51380224
#define AC_ELEMS  (NDEM * CC)          // 1024
#define ASP_ELEMS (NDEM * HH * WW)     // 12544

// native clang vector type — required by __builtin_nontemporal_load/store
typedef float fvec4 __attribute__((ext_vector_type(4)));

// ---------------------------------------------------------------------------
// Kernel 1: compute sigmoid gates (tiny; writes outputs 1 and 2 of d_out,
// which the main kernel then re-reads L2-hot).
// ---------------------------------------------------------------------------
__global__ void att_gates_kernel(const float* __restrict__ att_channel,
                                 const float* __restrict__ att_spatial,
                                 float* __restrict__ ac_out,    // AC_ELEMS
                                 float* __restrict__ asp_out)   // ASP_ELEMS
{
    int i = blockIdx.x * blockDim.x + threadIdx.x;
    const int total = AC_ELEMS + ASP_ELEMS;
    if (i >= total) return;
    if (i < AC_ELEMS) {
        float v = att_channel[i];
        ac_out[i] = 1.0f / (1.0f + expf(-v));
    } else {
        int j = i - AC_ELEMS;          // j = d*HW + h*WW + w
        int d = j / HW;
        int r = j - d * HW;
        int h = r / WW;
        int w = r - h * WW;
        float v = att_spatial[d * (HS * WS) + (h >> 1) * WS + (w >> 1)];
        asp_out[j] = 1.0f / (1.0f + expf(-v));
    }
}

// ---------------------------------------------------------------------------
// Kernel 2: one block per (n,c) plane. All index math is block-uniform;
// per-thread work is 3 full float4s + a 16-wide tail, fully unrolled.
// ---------------------------------------------------------------------------
__global__ __launch_bounds__(256) void att_apply_kernel(
    const fvec4* __restrict__ x,
    const int*   __restrict__ demog,     // NB
    const float* __restrict__ ac,        // [NDEM][CC]
    const fvec4* __restrict__ asp4,      // [NDEM][HW4]
    fvec4*       __restrict__ y)
{
    const int plane = blockIdx.x;         // n*CC + c
    const int n     = plane >> 8;         // CC = 256
    const int c     = plane & 255;
    const int d     = demog[n];           // block-uniform
    const float gc  = ac[(d << 8) + c];   // block-uniform

    const int t = threadIdx.x;
    const fvec4* __restrict__ xa = x + (size_t)plane * HW4;
    fvec4*       __restrict__ ya = y + (size_t)plane * HW4;
    const fvec4* __restrict__ ga = asp4 + d * HW4;

    // 784 = 3*256 + 16
    fvec4 x0 = __builtin_nontemporal_load(&xa[t]);
    fvec4 x1 = __builtin_nontemporal_load(&xa[t + 256]);
    fvec4 x2 = __builtin_nontemporal_load(&xa[t + 512]);
    fvec4 g0 = ga[t];
    fvec4 g1 = ga[t + 256];
    fvec4 g2 = ga[t + 512];

    fvec4 y0 = x0 * gc * g0;
    fvec4 y1 = x1 * gc * g1;
    fvec4 y2 = x2 * gc * g2;

    __builtin_nontemporal_store(y0, &ya[t]);
    __builtin_nontemporal_store(y1, &ya[t + 256]);
    __builtin_nontemporal_store(y2, &ya[t + 512]);

    if (t < 16) {
        int p = 768 + t;
        fvec4 xv = __builtin_nontemporal_load(&xa[p]);
        fvec4 gv = ga[p];
        fvec4 yv = xv * gc * gv;
        __builtin_nontemporal_store(yv, &ya[p]);
    }
}

// ---------------------------------------------------------------------------
extern "C" void kernel_launch(void* const* d_in, const int* in_sizes, int n_in,
                              void* d_out, int out_size, void* d_ws, size_t ws_size,
                              hipStream_t stream) {
    const float* x           = (const float*)d_in[0];
    const int*   demog       = (const int*)d_in[1];
    const float* att_channel = (const float*)d_in[2];
    const float* att_spatial = (const float*)d_in[3];

    float* y_out   = (float*)d_out;                       // Y_ELEMS
    float* ac_out  = y_out + Y_ELEMS;                     // AC_ELEMS
    float* asp_out = y_out + Y_ELEMS + AC_ELEMS;          // ASP_ELEMS

    // 1) gates (tiny)
    {
        int total  = AC_ELEMS + ASP_ELEMS;
        int blocks = (total + 255) / 256;
        att_gates_kernel<<<blocks, 256, 0, stream>>>(att_channel, att_spatial,
                                                     ac_out, asp_out);
    }

    // 2) main stream kernel: one block per (n,c) plane
    {
        int blocks = NB * CC;              // 16384
        att_apply_kernel<<<blocks, 256, 0, stream>>>(
            (const fvec4*)x, demog, ac_out, (const fvec4*)asp_out,
            (float4*)nullptr == nullptr ? (fvec4*)y_out : (fvec4*)y_out);
    }
}

// Round 4
// 69.594 us; speedup vs baseline: 1.2470x; 1.1017x over previous
//
#include <hip/hip_runtime.h>
#include <math.h>

// Problem constants (from reference)
#define NB   64      // batch
#define CC   256     // channels
#define HH   56
#define WW   56
#define NDEM 4
#define HS   28
#define WS   28

#define HW        (HH * WW)            // 3136
#define HW4       (HW / 4)             // 784 float4s per plane
#define Y_ELEMS   (NB * CC * HH * WW)  // 51380224
#define AC_ELEMS  (NDEM * CC)          // 1024
#define ASP_ELEMS (NDEM * HH * WW)     // 12544
#define PLANES    (NB * CC)            // 16384
#define GATE_BLOCKS ((AC_ELEMS + ASP_ELEMS + 255) / 256)   // 53

// native clang vector type — required by __builtin_nontemporal_load/store
typedef float fvec4 __attribute__((ext_vector_type(4)));
typedef float fvec2 __attribute__((ext_vector_type(2)));

__device__ __forceinline__ float sigmoidf_(float v) {
    return 1.0f / (1.0f + expf(-v));
}

// ---------------------------------------------------------------------------
// Fused kernel.
//   blocks [0, PLANES):            y = x * gc * gs for one (n,c) plane,
//                                  gates recomputed inline (no dependency).
//   blocks [PLANES, PLANES+53):    write the ac / asp outputs.
// ---------------------------------------------------------------------------
__global__ __launch_bounds__(256) void att_fused_kernel(
    const fvec4* __restrict__ x,
    const int*   __restrict__ demog,        // NB
    const float* __restrict__ att_channel,  // [NDEM][CC]
    const float* __restrict__ att_spatial,  // [NDEM][HS*WS]
    fvec4*       __restrict__ y,
    float*       __restrict__ ac_out,       // AC_ELEMS
    float*       __restrict__ asp_out)      // ASP_ELEMS
{
    const int b = blockIdx.x;
    const int t = threadIdx.x;

    if (b >= PLANES) {
        // ---- gate-table output path (53 blocks) ----
        int i = (b - PLANES) * 256 + t;
        if (i < AC_ELEMS) {
            ac_out[i] = sigmoidf_(att_channel[i]);
        } else if (i < AC_ELEMS + ASP_ELEMS) {
            int j = i - AC_ELEMS;          // j = d*HW + h*WW + w
            int d = j / HW;
            int r = j - d * HW;
            int h = r / WW;
            int w = r - h * WW;
            asp_out[j] = sigmoidf_(att_spatial[d * (HS * WS) + (h >> 1) * WS + (w >> 1)]);
        }
        return;
    }

    // ---- plane path ----
    const int n = b >> 8;                  // CC = 256
    const int c = b & 255;
    const int d = demog[n];                // block-uniform
    const float gc = sigmoidf_(att_channel[(d << 8) + c]);   // block-uniform

    const fvec4* __restrict__ xa = x + (size_t)b * HW4;
    fvec4*       __restrict__ ya = y + (size_t)b * HW4;
    const float* __restrict__ sa = att_spatial + d * (HS * WS);

    // spatial gate for plane-float4 index p:
    //   pos = 4p, h = p/14, w4 = p%14, hs = h>>1
    //   sources: sa[hs*28 + 2*w4], sa[hs*28 + 2*w4 + 1]  (aligned float2)
    //   gate = (s0, s0, s1, s1)
    #define GATE(p, gv)                                                     \
    {                                                                       \
        int h_  = (p) / 14;                                                 \
        int w4_ = (p) - h_ * 14;                                            \
        fvec2 a_ = *reinterpret_cast<const fvec2*>(                         \
                        &sa[(h_ >> 1) * WS + 2 * w4_]);                     \
        float s0_ = sigmoidf_(a_.x) * gc;                                   \
        float s1_ = sigmoidf_(a_.y) * gc;                                   \
        gv.x = s0_; gv.y = s0_; gv.z = s1_; gv.w = s1_;                     \
    }

    // 784 = 3*256 + 16
    fvec4 x0 = __builtin_nontemporal_load(&xa[t]);
    fvec4 x1 = __builtin_nontemporal_load(&xa[t + 256]);
    fvec4 x2 = __builtin_nontemporal_load(&xa[t + 512]);

    fvec4 g0, g1, g2;
    GATE(t,       g0);
    GATE(t + 256, g1);
    GATE(t + 512, g2);

    fvec4 y0 = x0 * g0;
    fvec4 y1 = x1 * g1;
    fvec4 y2 = x2 * g2;

    __builtin_nontemporal_store(y0, &ya[t]);
    __builtin_nontemporal_store(y1, &ya[t + 256]);
    __builtin_nontemporal_store(y2, &ya[t + 512]);

    if (t < 16) {
        int p = 768 + t;
        fvec4 xv = __builtin_nontemporal_load(&xa[p]);
        fvec4 gv;
        GATE(p, gv);
        fvec4 yv = xv * gv;
        __builtin_nontemporal_store(yv, &ya[p]);
    }
    #undef GATE
}

// ---------------------------------------------------------------------------
extern "C" void kernel_launch(void* const* d_in, const int* in_sizes, int n_in,
                              void* d_out, int out_size, void* d_ws, size_t ws_size,
                              hipStream_t stream) {
    const float* x           = (const float*)d_in[0];
    const int*   demog       = (const int*)d_in[1];
    const float* att_channel = (const float*)d_in[2];
    const float* att_spatial = (const float*)d_in[3];

    float* y_out   = (float*)d_out;                       // Y_ELEMS
    float* ac_out  = y_out + Y_ELEMS;                     // AC_ELEMS
    float* asp_out = y_out + Y_ELEMS + AC_ELEMS;          // ASP_ELEMS

    int blocks = PLANES + GATE_BLOCKS;    // 16384 + 53
    att_fused_kernel<<<blocks, 256, 0, stream>>>(
        (const fvec4*)x, demog, att_channel, att_spatial,
        (fvec4*)y_out, ac_out, asp_out);
}

// Round 5
// 65.201 us; speedup vs baseline: 1.3310x; 1.0674x over previous
//
#include <hip/hip_runtime.h>
#include <math.h>

// Problem constants (from reference)
#define NB   64      // batch
#define CC   256     // channels
#define HH   56
#define WW   56
#define NDEM 4
#define HS   28
#define WS   28

#define HW        (HH * WW)            // 3136
#define HW4       (HW / 4)             // 784 float4s per plane
#define Y_ELEMS   (NB * CC * HH * WW)  // 51380224
#define AC_ELEMS  (NDEM * CC)          // 1024
#define ASP_ELEMS (NDEM * HH * WW)     // 12544
#define PLANES    (NB * CC)            // 16384
#define GATE_BLOCKS ((AC_ELEMS + ASP_ELEMS + 255) / 256)   // 53

// native clang vector type — required by __builtin_nontemporal_load/store
typedef float fvec4 __attribute__((ext_vector_type(4)));
typedef float fvec2 __attribute__((ext_vector_type(2)));

__device__ __forceinline__ float sigmoidf_(float v) {
    return 1.0f / (1.0f + expf(-v));
}

// ---------------------------------------------------------------------------
// Fused kernel.
//   blocks [0, PLANES):            y = x * gc * gs for one (n,c) plane,
//                                  gates recomputed inline (no dependency).
//   blocks [PLANES, PLANES+53):    write the ac / asp outputs.
// Stores are PLAIN (through L2, write-combined); loads of x are nontemporal.
// ---------------------------------------------------------------------------
__global__ __launch_bounds__(256) void att_fused_kernel(
    const fvec4* __restrict__ x,
    const int*   __restrict__ demog,        // NB
    const float* __restrict__ att_channel,  // [NDEM][CC]
    const float* __restrict__ att_spatial,  // [NDEM][HS*WS]
    fvec4*       __restrict__ y,
    float*       __restrict__ ac_out,       // AC_ELEMS
    float*       __restrict__ asp_out)      // ASP_ELEMS
{
    const int b = blockIdx.x;
    const int t = threadIdx.x;

    if (b >= PLANES) {
        // ---- gate-table output path (53 blocks) ----
        int i = (b - PLANES) * 256 + t;
        if (i < AC_ELEMS) {
            ac_out[i] = sigmoidf_(att_channel[i]);
        } else if (i < AC_ELEMS + ASP_ELEMS) {
            int j = i - AC_ELEMS;          // j = d*HW + h*WW + w
            int d = j / HW;
            int r = j - d * HW;
            int h = r / WW;
            int w = r - h * WW;
            asp_out[j] = sigmoidf_(att_spatial[d * (HS * WS) + (h >> 1) * WS + (w >> 1)]);
        }
        return;
    }

    // ---- plane path ----
    const int n = b >> 8;                  // CC = 256
    const int c = b & 255;
    const int d = demog[n];                // block-uniform
    const float gc = sigmoidf_(att_channel[(d << 8) + c]);   // block-uniform

    const fvec4* __restrict__ xa = x + (size_t)b * HW4;
    fvec4*       __restrict__ ya = y + (size_t)b * HW4;
    const float* __restrict__ sa = att_spatial + d * (HS * WS);

    // spatial gate for plane-float4 index p:
    //   pos = 4p, h = p/14, w4 = p%14, hs = h>>1
    //   sources: sa[hs*28 + 2*w4], sa[hs*28 + 2*w4 + 1]  (aligned float2)
    //   gate = (s0, s0, s1, s1)
    #define GATE(p, gv)                                                     \
    {                                                                       \
        int h_  = (p) / 14;                                                 \
        int w4_ = (p) - h_ * 14;                                            \
        fvec2 a_ = *reinterpret_cast<const fvec2*>(                         \
                        &sa[(h_ >> 1) * WS + 2 * w4_]);                     \
        float s0_ = sigmoidf_(a_.x) * gc;                                   \
        float s1_ = sigmoidf_(a_.y) * gc;                                   \
        gv.x = s0_; gv.y = s0_; gv.z = s1_; gv.w = s1_;                     \
    }

    // 784 = 3*256 + 16
    fvec4 x0 = __builtin_nontemporal_load(&xa[t]);
    fvec4 x1 = __builtin_nontemporal_load(&xa[t + 256]);
    fvec4 x2 = __builtin_nontemporal_load(&xa[t + 512]);

    fvec4 g0, g1, g2;
    GATE(t,       g0);
    GATE(t + 256, g1);
    GATE(t + 512, g2);

    ya[t]       = x0 * g0;
    ya[t + 256] = x1 * g1;
    ya[t + 512] = x2 * g2;

    if (t < 16) {
        int p = 768 + t;
        fvec4 xv = __builtin_nontemporal_load(&xa[p]);
        fvec4 gv;
        GATE(p, gv);
        ya[p] = xv * gv;
    }
    #undef GATE
}

// ---------------------------------------------------------------------------
extern "C" void kernel_launch(void* const* d_in, const int* in_sizes, int n_in,
                              void* d_out, int out_size, void* d_ws, size_t ws_size,
                              hipStream_t stream) {
    const float* x           = (const float*)d_in[0];
    const int*   demog       = (const int*)d_in[1];
    const float* att_channel = (const float*)d_in[2];
    const float* att_spatial = (const float*)d_in[3];

    float* y_out   = (float*)d_out;                       // Y_ELEMS
    float* ac_out  = y_out + Y_ELEMS;                     // AC_ELEMS
    float* asp_out = y_out + Y_ELEMS + AC_ELEMS;          // ASP_ELEMS

    int blocks = PLANES + GATE_BLOCKS;    // 16384 + 53
    att_fused_kernel<<<blocks, 256, 0, stream>>>(
        (const fvec4*)x, demog, att_channel, att_spatial,
        (fvec4*)y_out, ac_out, asp_out);
}